// Round 6
// baseline (932.677 us; speedup 1.0000x reference)
//
#include <hip/hip_runtime.h>

typedef unsigned short u16;
typedef short short8 __attribute__((ext_vector_type(8)));
typedef unsigned short ushort8 __attribute__((ext_vector_type(8)));
typedef float f32x4 __attribute__((ext_vector_type(4)));

#define NN 32768L

__device__ __forceinline__ u16 f2bf(float f) {
  unsigned u = __float_as_uint(f);
  u += 0x7FFFu + ((u >> 16) & 1u);
  return (u16)(u >> 16);
}
__device__ __forceinline__ float bf2f(u16 u) {
  return __uint_as_float(((unsigned)u) << 16);
}

// ---------------- sentinel fill (env-contract violation reporter) ----------------
__global__ __launch_bounds__(256) void fill_f32_k(float* __restrict__ out, long n, float v) {
  long i = (long)blockIdx.x * 256 + threadIdx.x;
  if (i < n) out[i] = v;
}

// ---------------- elementwise cast f32 -> bf16 (8 elems/thread) ----------------
__global__ __launch_bounds__(256) void cast_bf16_k(const float* __restrict__ in,
                                                   u16* __restrict__ out, long n) {
  long i = ((long)blockIdx.x * 256 + threadIdx.x) * 8;
  if (i >= n) return;
  const float4* p = (const float4*)(in + i);
  float4 a = p[0], b = p[1];
  ushort8 r;
  r[0] = f2bf(a.x); r[1] = f2bf(a.y); r[2] = f2bf(a.z); r[3] = f2bf(a.w);
  r[4] = f2bf(b.x); r[5] = f2bf(b.y); r[6] = f2bf(b.z); r[7] = f2bf(b.w);
  *(ushort8*)(out + i) = r;
}

// ---------------- transpose + cast: in[R][C] f32 -> out[C][R] bf16 ----------------
__global__ __launch_bounds__(256) void transpose_cast(const float* __restrict__ in,
                                                      u16* __restrict__ out, int R, int C) {
  __shared__ float t[32][33];
  int c0 = blockIdx.x * 32, r0 = blockIdx.y * 32;
  int tx = threadIdx.x, ty = threadIdx.y;  // 32 x 8
#pragma unroll
  for (int j = 0; j < 32; j += 8)
    t[ty + j][tx] = in[(long)(r0 + ty + j) * C + c0 + tx];
  __syncthreads();
#pragma unroll
  for (int j = 0; j < 32; j += 8)
    out[(long)(c0 + ty + j) * R + r0 + tx] = f2bf(t[tx][ty + j]);
}

// ---------------- bf16 GEMM: C[M,N] = A @ Bt^T, 128x128x32, reg-staged LDS ----------------
// Row strides lda/ldb/ldc in elements; sA/sB/sC = batch (blockIdx.z) offsets in elements.
// EPI: 0 = plain bf16 store, 1 = bias+relu bf16, 2 = bias bf16
template <int EPI>
__global__ __launch_bounds__(256) void gemm_bt(const u16* __restrict__ A,
                                               const u16* __restrict__ Bt,
                                               u16* __restrict__ C, int K,
                                               int lda, int ldb, int ldc,
                                               long sA, long sB, long sC,
                                               const float* __restrict__ ep0) {
  __shared__ u16 As[4096];  // 128 rows x 32 cols, row-major
  __shared__ u16 Bs[4096];
  const int tid = threadIdx.x;
  const int wid = tid >> 6, lane = tid & 63;
  const int bx = blockIdx.x, by = blockIdx.y, bz = blockIdx.z;
  const u16* Ab = A + bz * sA + (long)by * 128 * lda;
  const u16* Bb = Bt + bz * sB + (long)bx * 128 * ldb;
  const int e0 = tid * 8;                // LDS element index this thread stages
  const int ar = e0 >> 5, ac = e0 & 31;  // tile row/col (rows 0..63; +64 for 2nd)
  const int r15 = lane & 15, kg = lane >> 4;
  const int wrow = (wid >> 1) * 64, wcol = (wid & 1) * 64;

  f32x4 acc[4][4];
  const f32x4 z4 = {0.f, 0.f, 0.f, 0.f};
#pragma unroll
  for (int mi = 0; mi < 4; ++mi)
#pragma unroll
    for (int ni = 0; ni < 4; ++ni) acc[mi][ni] = z4;

  for (int k0 = 0; k0 < K; k0 += 32) {
    short8 a0 = *(const short8*)(Ab + (long)ar * lda + k0 + ac);
    short8 a1 = *(const short8*)(Ab + (long)(ar + 64) * lda + k0 + ac);
    short8 b0 = *(const short8*)(Bb + (long)ar * ldb + k0 + ac);
    short8 b1 = *(const short8*)(Bb + (long)(ar + 64) * ldb + k0 + ac);
    *(short8*)(As + e0) = a0;
    *(short8*)(As + e0 + 2048) = a1;
    *(short8*)(Bs + e0) = b0;
    *(short8*)(Bs + e0 + 2048) = b1;
    __syncthreads();
    short8 af[4], bfr[4];
#pragma unroll
    for (int mi = 0; mi < 4; ++mi)
      af[mi] = *(const short8*)(As + (wrow + mi * 16 + r15) * 32 + kg * 8);
#pragma unroll
    for (int ni = 0; ni < 4; ++ni)
      bfr[ni] = *(const short8*)(Bs + (wcol + ni * 16 + r15) * 32 + kg * 8);
#pragma unroll
    for (int mi = 0; mi < 4; ++mi)
#pragma unroll
      for (int ni = 0; ni < 4; ++ni)
        acc[mi][ni] =
            __builtin_amdgcn_mfma_f32_16x16x32_bf16(af[mi], bfr[ni], acc[mi][ni], 0, 0, 0);
    __syncthreads();
  }

  u16* Cp = C + bz * sC;
  const long crow0 = (long)by * 128 + wrow;
  const int ccol0 = bx * 128 + wcol;
#pragma unroll
  for (int mi = 0; mi < 4; ++mi) {
#pragma unroll
    for (int ni = 0; ni < 4; ++ni) {
      const int gc = ccol0 + ni * 16 + r15;
#pragma unroll
      for (int r = 0; r < 4; ++r) {
        const long gr = crow0 + mi * 16 + kg * 4 + r;
        float v = acc[mi][ni][r];
        if (EPI == 1) { v += ep0[gc]; v = fmaxf(v, 0.f); }
        if (EPI == 2) { v += ep0[gc]; }
        Cp[gr * ldc + gc] = f2bf(v);
      }
    }
  }
}

// ---------------- att[n,h] = scale * sum_i x[n,i] * z[n, h*512+i]  (x is f32) ----------------
__global__ __launch_bounds__(256) void att_dot_k(const float* __restrict__ x,
                                                 const u16* __restrict__ zb,
                                                 float* __restrict__ att) {
  int wid = threadIdx.x >> 6, lane = threadIdx.x & 63;
  long n = (long)blockIdx.x * 4 + wid;  // row within this chunk
  const float4* xp = (const float4*)(x + n * 512 + lane * 8);
  float4 x0 = xp[0], x1 = xp[1];
  float xf[8] = {x0.x, x0.y, x0.z, x0.w, x1.x, x1.y, x1.z, x1.w};
  const float scale = 0.044194173824159216f;  // 1/sqrt(512)
#pragma unroll
  for (int h = 0; h < 4; ++h) {
    ushort8 zv = *(const ushort8*)(zb + n * 2048 + h * 512 + lane * 8);
    float s = 0.f;
#pragma unroll
    for (int j = 0; j < 8; ++j) s += xf[j] * bf2f(zv[j]);
#pragma unroll
    for (int o = 32; o; o >>= 1) s += __shfl_xor(s, o);
    if (lane == 0) att[n * 4 + h] = s * scale;
  }
}

// ---------------- softmax over nodes (axis 0), one block per head ----------------
__global__ __launch_bounds__(1024) void softmax_k(const float* __restrict__ att,
                                                  float* __restrict__ alpha) {
  int h = blockIdx.x;
  int tid = threadIdx.x;
  __shared__ float red[16];
  float lm = -1e30f;
  for (long i = tid; i < NN; i += 1024) lm = fmaxf(lm, att[i * 4 + h]);
#pragma unroll
  for (int o = 32; o; o >>= 1) lm = fmaxf(lm, __shfl_xor(lm, o));
  if ((tid & 63) == 0) red[tid >> 6] = lm;
  __syncthreads();
  float gm = red[0];
  for (int i = 1; i < 16; ++i) gm = fmaxf(gm, red[i]);
  __syncthreads();
  float ls = 0.f;
  for (long i = tid; i < NN; i += 1024) ls += __expf(att[i * 4 + h] - gm);
#pragma unroll
  for (int o = 32; o; o >>= 1) ls += __shfl_xor(ls, o);
  if ((tid & 63) == 0) red[tid >> 6] = ls;
  __syncthreads();
  float gs = 0.f;
  for (int i = 0; i < 16; ++i) gs += red[i];
  float inv = 1.0f / gs;
  for (long i = tid; i < NN; i += 1024)
    alpha[i * 4 + h] = __expf(att[i * 4 + h] - gm) * inv;
}

// ---------------- A'[r, h*512+i] = alpha[row0+r, h] * x[row0+r, i]  (x f32 -> bf16) ----------------
__global__ __launch_bounds__(256) void ascale_k(const float* __restrict__ x,
                                                const float* __restrict__ alpha,
                                                u16* __restrict__ out, long row0) {
  long e = ((long)blockIdx.x * 256 + threadIdx.x) * 8;  // flat elem in [rows, 2048]
  long r = e >> 11;
  int c = (int)(e & 2047);
  int h = c >> 9;
  float al = alpha[(row0 + r) * 4 + h];
  const float4* xp = (const float4*)(x + (row0 + r) * 512 + (c & 511));
  float4 x0 = xp[0], x1 = xp[1];
  ushort8 o;
  o[0] = f2bf(al * x0.x); o[1] = f2bf(al * x0.y);
  o[2] = f2bf(al * x0.z); o[3] = f2bf(al * x0.w);
  o[4] = f2bf(al * x1.x); o[5] = f2bf(al * x1.y);
  o[6] = f2bf(al * x1.z); o[7] = f2bf(al * x1.w);
  *(ushort8*)(out + e) = o;
}

// ---------------- fused residual + layernorm, one wave per 512-col row ----------------
// a bf16; resid f32 (RBF=0) or bf16 (RBF=1); OUTF: 0 = bf16 out, 1 = f32 out.
template <int RBF, int OUTF>
__global__ __launch_bounds__(256) void ln_k(const u16* __restrict__ a,
                                            const void* __restrict__ resid,
                                            const float* __restrict__ g,
                                            const float* __restrict__ b,
                                            void* __restrict__ out) {
  int wid = threadIdx.x >> 6, lane = threadIdx.x & 63;
  long row = (long)blockIdx.x * 4 + wid;
  ushort8 av = *(const ushort8*)(a + row * 512 + lane * 8);
  float v[8];
  if (RBF) {
    ushort8 rv = *(const ushort8*)((const u16*)resid + row * 512 + lane * 8);
#pragma unroll
    for (int j = 0; j < 8; ++j) v[j] = bf2f(av[j]) + bf2f(rv[j]);
  } else {
    const float4* rp = (const float4*)((const float*)resid + row * 512 + lane * 8);
    float4 r0 = rp[0], r1 = rp[1];
    float rr[8] = {r0.x, r0.y, r0.z, r0.w, r1.x, r1.y, r1.z, r1.w};
#pragma unroll
    for (int j = 0; j < 8; ++j) v[j] = bf2f(av[j]) + rr[j];
  }
  float s = 0.f, q = 0.f;
#pragma unroll
  for (int j = 0; j < 8; ++j) { s += v[j]; q += v[j] * v[j]; }
#pragma unroll
  for (int o = 32; o; o >>= 1) { s += __shfl_xor(s, o); q += __shfl_xor(q, o); }
  float mu = s * (1.0f / 512.0f);
  float var = q * (1.0f / 512.0f) - mu * mu;
  float rs = rsqrtf(var + 1e-5f);
  const float4* gp = (const float4*)(g + lane * 8);
  const float4* bp = (const float4*)(b + lane * 8);
  float4 g0 = gp[0], g1 = gp[1], b0 = bp[0], b1 = bp[1];
  float gg[8] = {g0.x, g0.y, g0.z, g0.w, g1.x, g1.y, g1.z, g1.w};
  float bb[8] = {b0.x, b0.y, b0.z, b0.w, b1.x, b1.y, b1.z, b1.w};
  float o_[8];
#pragma unroll
  for (int j = 0; j < 8; ++j) o_[j] = (v[j] - mu) * rs * gg[j] + bb[j];
  if (OUTF) {
    float4 q0 = {o_[0], o_[1], o_[2], o_[3]}, q1 = {o_[4], o_[5], o_[6], o_[7]};
    float4* op = (float4*)((float*)out + row * 512 + lane * 8);
    op[0] = q0;
    op[1] = q1;
  } else {
    ushort8 r;
#pragma unroll
    for (int j = 0; j < 8; ++j) r[j] = f2bf(o_[j]);
    *(ushort8*)((u16*)out + row * 512 + lane * 8) = r;
  }
}

extern "C" void kernel_launch(void* const* d_in, const int* in_sizes, int n_in,
                              void* d_out, int out_size, void* d_ws, size_t ws_size,
                              hipStream_t stream) {
  // ---- environment-contract check: write decodable sentinel if violated ----
  // err ~= sentinel value: 200+10k = in_sizes[k] mismatch; 390 = n_in != 14;
  // 400 = out_size wrong; 500 + ws_size/16MB = workspace too small.
  static const int EXPS[14] = {16777216, 16777216, 1048576, 32768, 1048576, 1048576,
                               1048576,  1048576,  524288,  1024,  524288,  512,
                               512,      512};
  float sv = 0.f;
  if (n_in != 14) {
    sv = 390.f;
  } else {
    for (int i = 0; i < 14; ++i)
      if (in_sizes[i] != EXPS[i]) { sv = 200.f + 10.f * i; break; }
  }
  if (sv == 0.f && out_size != 16777216) sv = 400.f;
  if (sv == 0.f && ws_size < 116391936UL) sv = 500.f + (float)(ws_size >> 24);
  if (sv != 0.f) {
    fill_f32_k<<<65536, 256, 0, stream>>>((float*)d_out, 16777216L, sv);
    return;
  }

  const float* x   = (const float*)d_in[0];
  const float* ih  = (const float*)d_in[1];
  const float* Wq  = (const float*)d_in[4];
  const float* Wk  = (const float*)d_in[5];
  const float* Wv  = (const float*)d_in[6];
  const float* Wc  = (const float*)d_in[7];
  const float* W1  = (const float*)d_in[8];
  const float* b1  = (const float*)d_in[9];
  const float* W2  = (const float*)d_in[10];
  const float* b2  = (const float*)d_in[11];
  const float* lng = (const float*)d_in[12];
  const float* lnb = (const float*)d_in[13];

  // ---- workspace: 112 MB ----
  // A [0,32MB):   yb -> apc chunk -> f1 chunk
  // B [32,64MB):  zc chunk -> mo chunk -> g2 full
  // H [64,96MB):  h1 bf16
  // W [96,112MB): weights + att/alpha
  char* w = (char*)d_ws;
  u16* yb   = (u16*)(w + 0L);
  u16* apc  = (u16*)(w + 0L);
  u16* f1c  = (u16*)(w + 0L);
  u16* zc   = (u16*)(w + 33554432L);
  u16* moc  = (u16*)(w + 33554432L);
  u16* g2   = (u16*)(w + 33554432L);
  u16* h1   = (u16*)(w + 67108864L);
  char* wb  = w + 100663296L;
  u16* Wqb  = (u16*)(wb + 0L);          // 2MB [4][512][512]
  u16* Wkb  = (u16*)(wb + 2097152L);    // 2MB
  u16* Wvb  = (u16*)(wb + 4194304L);    // 2MB
  u16* Wct  = (u16*)(wb + 6291456L);    // 2MB [512,2048] Wc^T
  u16* Mcat = (u16*)(wb + 8388608L);    // 2MB [2048,512] M_h = Wq_h Wk_h^T
  u16* Pt   = (u16*)(wb + 10485760L);   // 2MB [512,2048] Pt[d,h*512+i]=(Wv_h Wc_h)[i,d]
  u16* W1t  = (u16*)(wb + 12582912L);   // 1MB [1024,512]
  u16* W2t  = (u16*)(wb + 13631488L);   // 1MB [512,1024]
  float* att   = (float*)(wb + 14680064L);  // 0.5MB [N,4]
  float* alpha = (float*)(wb + 15204352L);  // 0.5MB [N,4]
  // end = 100663296 + 15728640 = 116,391,936 bytes

  dim3 b256(256);

  // ---- prep ----
  cast_bf16_k<<<8192, b256, 0, stream>>>(ih, yb, 16777216L);
  cast_bf16_k<<<512, b256, 0, stream>>>(Wq, Wqb, 1048576L);
  cast_bf16_k<<<512, b256, 0, stream>>>(Wk, Wkb, 1048576L);
  cast_bf16_k<<<512, b256, 0, stream>>>(Wv, Wvb, 1048576L);
  transpose_cast<<<dim3(16, 64), dim3(32, 8), 0, stream>>>(Wc, Wct, 2048, 512);
  transpose_cast<<<dim3(32, 16), dim3(32, 8), 0, stream>>>(W1, W1t, 512, 1024);
  transpose_cast<<<dim3(16, 32), dim3(32, 8), 0, stream>>>(W2, W2t, 1024, 512);

  // ---- Mcat[(h*512+i), j] = sum_o Wq[h,i,o] Wk[h,j,o] ----
  gemm_bt<0><<<dim3(4, 4, 4), b256, 0, stream>>>(Wqb, Wkb, Mcat, 512, 512, 512, 512,
                                                 262144L, 262144L, 262144L, nullptr);
  // ---- Pt[d', h*512+i] = sum_d Wc[h*512+d, d'] * Wv[h,i,d] ----
  gemm_bt<0><<<dim3(4, 4, 4), b256, 0, stream>>>(Wct, Wvb, Pt, 512, 2048, 512, 2048,
                                                 512L, 262144L, 512L, nullptr);

  // ---- att: z in 8 chunks of 4096 rows (z discarded after dot) ----
  for (int c = 0; c < 8; ++c) {
    long r0 = (long)c * 4096;
    gemm_bt<0><<<dim3(16, 32), b256, 0, stream>>>(yb + r0 * 512, Mcat, zc, 512,
                                                  512, 512, 2048, 0L, 0L, 0L, nullptr);
    att_dot_k<<<1024, b256, 0, stream>>>(x + r0 * 512, zc, att + r0 * 4);
  }
  softmax_k<<<4, 1024, 0, stream>>>(att, alpha);

  // ---- mo + LN1 in 4 chunks of 8192 rows: A'=alpha*x, mo=A'@Pt^T, h1=LN(mo+x) ----
  for (int c = 0; c < 4; ++c) {
    long r0 = (long)c * 8192;
    ascale_k<<<8192, b256, 0, stream>>>(x, alpha, apc, r0);
    gemm_bt<0><<<dim3(4, 64), b256, 0, stream>>>(apc, Pt, moc, 2048,
                                                 2048, 2048, 512, 0L, 0L, 0L, nullptr);
    ln_k<0, 0><<<2048, b256, 0, stream>>>(moc, x + r0 * 512, lng, lnb, h1 + r0 * 512);
  }

  // ---- FFN in 4 chunks of 8192 rows: f1=relu(h1@W1+b1), g2=f1@W2+b2 ----
  for (int c = 0; c < 4; ++c) {
    long r0 = (long)c * 8192;
    gemm_bt<1><<<dim3(8, 64), b256, 0, stream>>>(h1 + r0 * 512, W1t, f1c, 512,
                                                 512, 512, 1024, 0L, 0L, 0L, b1);
    gemm_bt<2><<<dim3(4, 64), b256, 0, stream>>>(f1c, W2t, g2 + r0 * 512, 1024,
                                                 1024, 1024, 512, 0L, 0L, 0L, b2);
  }

  // ---- out = LN(g2 + h1) -> d_out as FLOAT32 (reference output dtype!) ----
  ln_k<1, 1><<<8192, b256, 0, stream>>>(g2, h1, lng, lnb, d_out);
}

// Round 7
// 764.515 us; speedup vs baseline: 1.2200x; 1.2200x over previous
//
#include <hip/hip_runtime.h>

typedef unsigned short u16;
typedef short short8 __attribute__((ext_vector_type(8)));
typedef unsigned short ushort8 __attribute__((ext_vector_type(8)));
typedef float f32x4 __attribute__((ext_vector_type(4)));

#define NN 32768L

__device__ __forceinline__ u16 f2bf(float f) {
  unsigned u = __float_as_uint(f);
  u += 0x7FFFu + ((u >> 16) & 1u);
  return (u16)(u >> 16);
}
__device__ __forceinline__ float bf2f(u16 u) {
  return __uint_as_float(((unsigned)u) << 16);
}

// ---------------- fill (sentinel + att zero-init) ----------------
__global__ __launch_bounds__(256) void fill_f32_k(float* __restrict__ out, long n, float v) {
  long i = (long)blockIdx.x * 256 + threadIdx.x;
  if (i < n) out[i] = v;
}

// ---------------- elementwise cast f32 -> bf16 (8 elems/thread) ----------------
__global__ __launch_bounds__(256) void cast_bf16_k(const float* __restrict__ in,
                                                   u16* __restrict__ out, long n) {
  long i = ((long)blockIdx.x * 256 + threadIdx.x) * 8;
  if (i >= n) return;
  const float4* p = (const float4*)(in + i);
  float4 a = p[0], b = p[1];
  ushort8 r;
  r[0] = f2bf(a.x); r[1] = f2bf(a.y); r[2] = f2bf(a.z); r[3] = f2bf(a.w);
  r[4] = f2bf(b.x); r[5] = f2bf(b.y); r[6] = f2bf(b.z); r[7] = f2bf(b.w);
  *(ushort8*)(out + i) = r;
}

// ---------------- transpose + cast: in[R][C] f32 -> out[C][R] bf16 ----------------
__global__ __launch_bounds__(256) void transpose_cast(const float* __restrict__ in,
                                                      u16* __restrict__ out, int R, int C) {
  __shared__ float t[32][33];
  int c0 = blockIdx.x * 32, r0 = blockIdx.y * 32;
  int tx = threadIdx.x, ty = threadIdx.y;  // 32 x 8
#pragma unroll
  for (int j = 0; j < 32; j += 8)
    t[ty + j][tx] = in[(long)(r0 + ty + j) * C + c0 + tx];
  __syncthreads();
#pragma unroll
  for (int j = 0; j < 32; j += 8)
    out[(long)(c0 + ty + j) * R + r0 + tx] = f2bf(t[tx][ty + j]);
}

// ---------------- bf16 GEMM: C[M,N] = A @ Bt^T, 128x128x32, reg-staged LDS ----------------
// EPI: 0 plain bf16, 1 bias+relu bf16, 2 bias bf16,
//      3 att-dot epilogue: att[row,h] += scale * sum_col C_tile[row,col]*x[row,col&511]
// ASRC: 0 = A from bf16 ptr; 1 = A[n,k] = alf[n, k>>9] * xf[n, k&511]  (fused ascale)
template <int EPI, int ASRC>
__global__ __launch_bounds__(256) void gemm_bt(const u16* __restrict__ A,
                                               const u16* __restrict__ Bt,
                                               void* __restrict__ C, int K,
                                               int lda, int ldb, int ldc,
                                               long sA, long sB, long sC,
                                               const float* __restrict__ ep0,
                                               const float* __restrict__ xf,
                                               const float* __restrict__ alf) {
  __shared__ u16 As[4096];  // 128 rows x 32 cols, row-major
  __shared__ u16 Bs[4096];
  const int tid = threadIdx.x;
  const int wid = tid >> 6, lane = tid & 63;
  const int bx = blockIdx.x, by = blockIdx.y, bz = blockIdx.z;
  const u16* Ab = A + bz * sA + (long)by * 128 * lda;
  const u16* Bb = Bt + bz * sB + (long)bx * 128 * ldb;
  const int e0 = tid * 8;                // LDS element index this thread stages
  const int ar = e0 >> 5, ac = e0 & 31;  // tile row/col (rows 0..63; +64 for 2nd)
  const int r15 = lane & 15, kg = lane >> 4;
  const int wrow = (wid >> 1) * 64, wcol = (wid & 1) * 64;

  f32x4 acc[4][4];
  const f32x4 z4 = {0.f, 0.f, 0.f, 0.f};
#pragma unroll
  for (int mi = 0; mi < 4; ++mi)
#pragma unroll
    for (int ni = 0; ni < 4; ++ni) acc[mi][ni] = z4;

  for (int k0 = 0; k0 < K; k0 += 32) {
    short8 a0, a1;
    if (ASRC == 0) {
      a0 = *(const short8*)(Ab + (long)ar * lda + k0 + ac);
      a1 = *(const short8*)(Ab + (long)(ar + 64) * lda + k0 + ac);
    } else {
      const int hh = (k0 + ac) >> 9, cc = (k0 + ac) & 511;
      const long r0a = (long)by * 128 + ar;
      const float al0 = alf[r0a * 4 + hh];
      const float al1 = alf[(r0a + 64) * 4 + hh];
      const float4* p0 = (const float4*)(xf + r0a * 512 + cc);
      const float4* p1 = (const float4*)(xf + (r0a + 64) * 512 + cc);
      float4 u0 = p0[0], u1 = p0[1], v0 = p1[0], v1 = p1[1];
      a0[0] = (short)f2bf(al0 * u0.x); a0[1] = (short)f2bf(al0 * u0.y);
      a0[2] = (short)f2bf(al0 * u0.z); a0[3] = (short)f2bf(al0 * u0.w);
      a0[4] = (short)f2bf(al0 * u1.x); a0[5] = (short)f2bf(al0 * u1.y);
      a0[6] = (short)f2bf(al0 * u1.z); a0[7] = (short)f2bf(al0 * u1.w);
      a1[0] = (short)f2bf(al1 * v0.x); a1[1] = (short)f2bf(al1 * v0.y);
      a1[2] = (short)f2bf(al1 * v0.z); a1[3] = (short)f2bf(al1 * v0.w);
      a1[4] = (short)f2bf(al1 * v1.x); a1[5] = (short)f2bf(al1 * v1.y);
      a1[6] = (short)f2bf(al1 * v1.z); a1[7] = (short)f2bf(al1 * v1.w);
    }
    short8 b0 = *(const short8*)(Bb + (long)ar * ldb + k0 + ac);
    short8 b1 = *(const short8*)(Bb + (long)(ar + 64) * ldb + k0 + ac);
    *(short8*)(As + e0) = a0;
    *(short8*)(As + e0 + 2048) = a1;
    *(short8*)(Bs + e0) = b0;
    *(short8*)(Bs + e0 + 2048) = b1;
    __syncthreads();
    short8 af[4], bfr[4];
#pragma unroll
    for (int mi = 0; mi < 4; ++mi)
      af[mi] = *(const short8*)(As + (wrow + mi * 16 + r15) * 32 + kg * 8);
#pragma unroll
    for (int ni = 0; ni < 4; ++ni)
      bfr[ni] = *(const short8*)(Bs + (wcol + ni * 16 + r15) * 32 + kg * 8);
#pragma unroll
    for (int mi = 0; mi < 4; ++mi)
#pragma unroll
      for (int ni = 0; ni < 4; ++ni)
        acc[mi][ni] =
            __builtin_amdgcn_mfma_f32_16x16x32_bf16(af[mi], bfr[ni], acc[mi][ni], 0, 0, 0);
    __syncthreads();
  }

  const long crow0 = (long)by * 128 + wrow;
  const int ccol0 = bx * 128 + wcol;

  if (EPI == 3) {
    // att-dot: reduce over this tile's 64 columns (within one head), atomic into att
    const int hh = ccol0 >> 9;
    const int cb = (ccol0 & 511) + r15;
    float* att = (float*)C;
    const float scale = 0.044194173824159216f;  // 1/sqrt(512)
#pragma unroll
    for (int mi = 0; mi < 4; ++mi) {
#pragma unroll
      for (int r = 0; r < 4; ++r) {
        const long gr = crow0 + mi * 16 + kg * 4 + r;
        float p = 0.f;
#pragma unroll
        for (int ni = 0; ni < 4; ++ni)
          p += acc[mi][ni][r] * xf[gr * 512 + cb + ni * 16];
        p += __shfl_xor(p, 1); p += __shfl_xor(p, 2);
        p += __shfl_xor(p, 4); p += __shfl_xor(p, 8);
        if (r15 == 0) atomicAdd(att + gr * 4 + hh, p * scale);
      }
    }
    return;
  }

  u16* Cp = (u16*)C + bz * sC;
#pragma unroll
  for (int mi = 0; mi < 4; ++mi) {
#pragma unroll
    for (int ni = 0; ni < 4; ++ni) {
      const int gc = ccol0 + ni * 16 + r15;
#pragma unroll
      for (int r = 0; r < 4; ++r) {
        const long gr = crow0 + mi * 16 + kg * 4 + r;
        float v = acc[mi][ni][r];
        if (EPI == 1) { v += ep0[gc]; v = fmaxf(v, 0.f); }
        if (EPI == 2) { v += ep0[gc]; }
        Cp[gr * ldc + gc] = f2bf(v);
      }
    }
  }
}

// ---------------- softmax over nodes (axis 0), one block per head ----------------
__global__ __launch_bounds__(1024) void softmax_k(const float* __restrict__ att,
                                                  float* __restrict__ alpha) {
  int h = blockIdx.x;
  int tid = threadIdx.x;
  __shared__ float red[16];
  float lm = -1e30f;
  for (long i = tid; i < NN; i += 1024) lm = fmaxf(lm, att[i * 4 + h]);
#pragma unroll
  for (int o = 32; o; o >>= 1) lm = fmaxf(lm, __shfl_xor(lm, o));
  if ((tid & 63) == 0) red[tid >> 6] = lm;
  __syncthreads();
  float gm = red[0];
  for (int i = 1; i < 16; ++i) gm = fmaxf(gm, red[i]);
  __syncthreads();
  float ls = 0.f;
  for (long i = tid; i < NN; i += 1024) ls += __expf(att[i * 4 + h] - gm);
#pragma unroll
  for (int o = 32; o; o >>= 1) ls += __shfl_xor(ls, o);
  if ((tid & 63) == 0) red[tid >> 6] = ls;
  __syncthreads();
  float gs = 0.f;
  for (int i = 0; i < 16; ++i) gs += red[i];
  float inv = 1.0f / gs;
  for (long i = tid; i < NN; i += 1024)
    alpha[i * 4 + h] = __expf(att[i * 4 + h] - gm) * inv;
}

// ---------------- fused residual + layernorm, one wave per 512-col row ----------------
// a bf16; resid f32 (RBF=0) or bf16 (RBF=1); OUTF: 0 = bf16 out, 1 = f32 out.
template <int RBF, int OUTF>
__global__ __launch_bounds__(256) void ln_k(const u16* __restrict__ a,
                                            const void* __restrict__ resid,
                                            const float* __restrict__ g,
                                            const float* __restrict__ b,
                                            void* __restrict__ out) {
  int wid = threadIdx.x >> 6, lane = threadIdx.x & 63;
  long row = (long)blockIdx.x * 4 + wid;
  ushort8 av = *(const ushort8*)(a + row * 512 + lane * 8);
  float v[8];
  if (RBF) {
    ushort8 rv = *(const ushort8*)((const u16*)resid + row * 512 + lane * 8);
#pragma unroll
    for (int j = 0; j < 8; ++j) v[j] = bf2f(av[j]) + bf2f(rv[j]);
  } else {
    const float4* rp = (const float4*)((const float*)resid + row * 512 + lane * 8);
    float4 r0 = rp[0], r1 = rp[1];
    float rr[8] = {r0.x, r0.y, r0.z, r0.w, r1.x, r1.y, r1.z, r1.w};
#pragma unroll
    for (int j = 0; j < 8; ++j) v[j] = bf2f(av[j]) + rr[j];
  }
  float s = 0.f, q = 0.f;
#pragma unroll
  for (int j = 0; j < 8; ++j) { s += v[j]; q += v[j] * v[j]; }
#pragma unroll
  for (int o = 32; o; o >>= 1) { s += __shfl_xor(s, o); q += __shfl_xor(q, o); }
  float mu = s * (1.0f / 512.0f);
  float var = q * (1.0f / 512.0f) - mu * mu;
  float rs = rsqrtf(var + 1e-5f);
  const float4* gp = (const float4*)(g + lane * 8);
  const float4* bp = (const float4*)(b + lane * 8);
  float4 g0 = gp[0], g1 = gp[1], b0 = bp[0], b1 = bp[1];
  float gg[8] = {g0.x, g0.y, g0.z, g0.w, g1.x, g1.y, g1.z, g1.w};
  float bb[8] = {b0.x, b0.y, b0.z, b0.w, b1.x, b1.y, b1.z, b1.w};
  float o_[8];
#pragma unroll
  for (int j = 0; j < 8; ++j) o_[j] = (v[j] - mu) * rs * gg[j] + bb[j];
  if (OUTF) {
    float4 q0 = {o_[0], o_[1], o_[2], o_[3]}, q1 = {o_[4], o_[5], o_[6], o_[7]};
    float4* op = (float4*)((float*)out + row * 512 + lane * 8);
    op[0] = q0;
    op[1] = q1;
  } else {
    ushort8 r;
#pragma unroll
    for (int j = 0; j < 8; ++j) r[j] = f2bf(o_[j]);
    *(ushort8*)((u16*)out + row * 512 + lane * 8) = r;
  }
}

extern "C" void kernel_launch(void* const* d_in, const int* in_sizes, int n_in,
                              void* d_out, int out_size, void* d_ws, size_t ws_size,
                              hipStream_t stream) {
  // ---- environment-contract check: write decodable sentinel if violated ----
  static const int EXPS[14] = {16777216, 16777216, 1048576, 32768, 1048576, 1048576,
                               1048576,  1048576,  524288,  1024,  524288,  512,
                               512,      512};
  float sv = 0.f;
  if (n_in != 14) {
    sv = 390.f;
  } else {
    for (int i = 0; i < 14; ++i)
      if (in_sizes[i] != EXPS[i]) { sv = 200.f + 10.f * i; break; }
  }
  if (sv == 0.f && out_size != 16777216) sv = 400.f;
  if (sv == 0.f && ws_size < 149946368UL) sv = 500.f + (float)(ws_size >> 24);
  if (sv != 0.f) {
    fill_f32_k<<<65536, 256, 0, stream>>>((float*)d_out, 16777216L, sv);
    return;
  }

  const float* x   = (const float*)d_in[0];
  const float* ih  = (const float*)d_in[1];
  const float* Wq  = (const float*)d_in[4];
  const float* Wk  = (const float*)d_in[5];
  const float* Wv  = (const float*)d_in[6];
  const float* Wc  = (const float*)d_in[7];
  const float* W1  = (const float*)d_in[8];
  const float* b1  = (const float*)d_in[9];
  const float* W2  = (const float*)d_in[10];
  const float* b2  = (const float*)d_in[11];
  const float* lng = (const float*)d_in[12];
  const float* lnb = (const float*)d_in[13];

  // ---- workspace: 143 MB ----
  // [0,32)    yb (att phase);   [0,64) f1 (FFN phase, yb dead)
  // [64,96)   moc (mo phase) -> g2 (FFN phase, moc dead after LN1)
  // [96,128)  h1 bf16
  // [128,143) weights + att/alpha
  char* w = (char*)d_ws;
  u16* yb   = (u16*)(w + 0L);
  u16* f1   = (u16*)(w + 0L);
  u16* moc  = (u16*)(w + 67108864L);
  u16* g2   = (u16*)(w + 67108864L);
  u16* h1   = (u16*)(w + 100663296L);
  char* wb  = w + 134217728L;
  u16* Wqb  = (u16*)(wb + 0L);          // 2MB [4][512][512]
  u16* Wkb  = (u16*)(wb + 2097152L);    // 2MB
  u16* Wvb  = (u16*)(wb + 4194304L);    // 2MB
  u16* Wct  = (u16*)(wb + 6291456L);    // 2MB [512,2048] Wc^T
  u16* Mcat = (u16*)(wb + 8388608L);    // 2MB [2048,512] M_h = Wq_h Wk_h^T
  u16* Pt   = (u16*)(wb + 10485760L);   // 2MB [512,2048] Pt[d,h*512+i]=(Wv_h Wc_h)[i,d]
  u16* W1t  = (u16*)(wb + 12582912L);   // 1MB [1024,512]
  u16* W2t  = (u16*)(wb + 13631488L);   // 1MB [512,1024]
  float* att   = (float*)(wb + 14680064L);  // 0.5MB [N,4]
  float* alpha = (float*)(wb + 15204352L);  // 0.5MB [N,4]
  // end = 134217728 + 15728640 = 149,946,368

  dim3 b256(256);

  // ---- prep ----
  cast_bf16_k<<<8192, b256, 0, stream>>>(ih, yb, 16777216L);
  cast_bf16_k<<<512, b256, 0, stream>>>(Wq, Wqb, 1048576L);
  cast_bf16_k<<<512, b256, 0, stream>>>(Wk, Wkb, 1048576L);
  cast_bf16_k<<<512, b256, 0, stream>>>(Wv, Wvb, 1048576L);
  transpose_cast<<<dim3(16, 64), dim3(32, 8), 0, stream>>>(Wc, Wct, 2048, 512);
  transpose_cast<<<dim3(32, 16), dim3(32, 8), 0, stream>>>(W1, W1t, 512, 1024);
  transpose_cast<<<dim3(16, 32), dim3(32, 8), 0, stream>>>(W2, W2t, 1024, 512);
  fill_f32_k<<<512, b256, 0, stream>>>(att, 131072L, 0.f);

  // ---- Mcat[(h*512+i), j] = sum_o Wq[h,i,o] Wk[h,j,o] ----
  gemm_bt<0, 0><<<dim3(4, 4, 4), b256, 0, stream>>>(
      Wqb, Wkb, Mcat, 512, 512, 512, 512, 262144L, 262144L, 262144L,
      nullptr, nullptr, nullptr);
  // ---- Pt[d', h*512+i] = sum_d Wc[h*512+d, d'] * Wv[h,i,d] ----
  gemm_bt<0, 0><<<dim3(4, 4, 4), b256, 0, stream>>>(
      Wct, Wvb, Pt, 512, 2048, 512, 2048, 512L, 262144L, 512L,
      nullptr, nullptr, nullptr);

  // ---- att (fused): z-tile = yb @ Mcat^T, epilogue dots with x -> atomic att ----
  gemm_bt<3, 0><<<dim3(16, 256), b256, 0, stream>>>(
      yb, Mcat, att, 512, 512, 512, 0, 0L, 0L, 0L, nullptr, x, nullptr);
  softmax_k<<<4, 1024, 0, stream>>>(att, alpha);

  // ---- mo = A' @ Pt^T, A'[n,k]=alpha[n,k>>9]*x[n,k&511] staged on the fly ----
  gemm_bt<0, 1><<<dim3(4, 256), b256, 0, stream>>>(
      nullptr, Pt, moc, 2048, 0, 2048, 512, 0L, 0L, 0L, nullptr, x, alpha);

  // ---- h1 = LN(mo + x) ----
  ln_k<0, 0><<<8192, b256, 0, stream>>>(moc, x, lng, lnb, h1);

  // ---- FFN ----
  gemm_bt<1, 0><<<dim3(8, 256), b256, 0, stream>>>(
      h1, W1t, f1, 512, 512, 512, 1024, 0L, 0L, 0L, b1, nullptr, nullptr);
  gemm_bt<2, 0><<<dim3(4, 256), b256, 0, stream>>>(
      f1, W2t, g2, 1024, 1024, 1024, 512, 0L, 0L, 0L, b2, nullptr, nullptr);

  // ---- out = LN(g2 + h1) -> d_out f32 ----
  ln_k<1, 1><<<8192, b256, 0, stream>>>(g2, h1, lng, lnb, d_out);
}